// Round 1
// baseline (10720.309 us; speedup 1.0000x reference)
//
#include <hip/hip_runtime.h>
#include <math.h>

#define NTOK 2048
#define DIMD 512
#define VOC  32000
#define SSTK 32
#define NDEP 8
#define FEPS 1e-6f
#define FTHR 0.9999f

#define BM 64
#define BN 64
#define BK 16
#define PAD 4

static __device__ __forceinline__ float sigmoidf_(float x) {
    return 1.0f / (1.0f + expf(-x));
}

// ---------------------------------------------------------------------------
// Embedding gather + zero-init of accumulators (runs every call; ws is poisoned)
// ---------------------------------------------------------------------------
__global__ __launch_bounds__(256) void k_embed(
    const int* __restrict__ tok,
    const float* __restrict__ er, const float* __restrict__ ei,
    float* __restrict__ zr, float* __restrict__ zi,
    float* __restrict__ outr, float* __restrict__ outi,
    float* __restrict__ cum)
{
    const int i = blockIdx.x;
    const int t = tok[i];
    for (int d = threadIdx.x; d < DIMD; d += 256) {
        zr[(size_t)i * DIMD + d] = er[(size_t)t * DIMD + d];
        zi[(size_t)i * DIMD + d] = ei[(size_t)t * DIMD + d];
        outr[(size_t)i * DIMD + d] = 0.0f;
        outi[(size_t)i * DIMD + d] = 0.0f;
    }
    if (threadIdx.x == 0) cum[i] = 0.0f;
}

// ---------------------------------------------------------------------------
// Complex GEMM (NT): Cr = Ar*Br^T - Ai*Bi^T ; Ci = Ai*Br^T + Ar*Bi^T
// A: M x K row-major ; B: Ncol x K row-major ; C: M x Ncol
// ---------------------------------------------------------------------------
__global__ __launch_bounds__(256) void k_cgemm_nt(
    const float* __restrict__ Ar, const float* __restrict__ Ai,
    const float* __restrict__ Br, const float* __restrict__ Bi,
    float* __restrict__ Cr, float* __restrict__ Ci,
    int M, int Ncol, int K)
{
    __shared__ float sAr[BK][BM + PAD], sAi[BK][BM + PAD];
    __shared__ float sBr[BK][BN + PAD], sBi[BK][BN + PAD];
    const int tid = threadIdx.x;
    const int tx = tid & 15, ty = tid >> 4;
    const int row0 = blockIdx.y * BM, col0 = blockIdx.x * BN;
    float cr[4][4] = {{0.f}}, ci[4][4] = {{0.f}};
    for (int k0 = 0; k0 < K; k0 += BK) {
        for (int l = tid; l < BM * BK; l += 256) {
            int m = l >> 4, kk = l & 15;
            sAr[kk][m] = Ar[(size_t)(row0 + m) * K + k0 + kk];
            sAi[kk][m] = Ai[(size_t)(row0 + m) * K + k0 + kk];
            sBr[kk][m] = Br[(size_t)(col0 + m) * K + k0 + kk];
            sBi[kk][m] = Bi[(size_t)(col0 + m) * K + k0 + kk];
        }
        __syncthreads();
#pragma unroll
        for (int kk = 0; kk < BK; ++kk) {
            float a_r[4], a_i[4], b_r[4], b_i[4];
#pragma unroll
            for (int i = 0; i < 4; i++) { a_r[i] = sAr[kk][ty * 4 + i]; a_i[i] = sAi[kk][ty * 4 + i]; }
#pragma unroll
            for (int j = 0; j < 4; j++) { b_r[j] = sBr[kk][tx * 4 + j]; b_i[j] = sBi[kk][tx * 4 + j]; }
#pragma unroll
            for (int i = 0; i < 4; i++) {
#pragma unroll
                for (int j = 0; j < 4; j++) {
                    cr[i][j] += a_r[i] * b_r[j] - a_i[i] * b_i[j];
                    ci[i][j] += a_i[i] * b_r[j] + a_r[i] * b_i[j];
                }
            }
        }
        __syncthreads();
    }
#pragma unroll
    for (int i = 0; i < 4; i++) {
#pragma unroll
        for (int j = 0; j < 4; j++) {
            size_t idx = (size_t)(row0 + ty * 4 + i) * Ncol + (col0 + tx * 4 + j);
            Cr[idx] = cr[i][j];
            Ci[idx] = ci[i][j];
        }
    }
}

// ---------------------------------------------------------------------------
// Scores: S = (Qr*Kr^T + Qi*Ki^T) * scale    (N x N, K = DIMD)
// ---------------------------------------------------------------------------
__global__ __launch_bounds__(256) void k_score_gemm(
    const float* __restrict__ Qr, const float* __restrict__ Qi,
    const float* __restrict__ Kr, const float* __restrict__ Ki,
    float* __restrict__ S, int N, int K, float scale)
{
    __shared__ float sQr[BK][BM + PAD], sQi[BK][BM + PAD];
    __shared__ float sKr[BK][BN + PAD], sKi[BK][BN + PAD];
    const int tid = threadIdx.x;
    const int tx = tid & 15, ty = tid >> 4;
    const int row0 = blockIdx.y * BM, col0 = blockIdx.x * BN;
    float acc[4][4] = {{0.f}};
    for (int k0 = 0; k0 < K; k0 += BK) {
        for (int l = tid; l < BM * BK; l += 256) {
            int m = l >> 4, kk = l & 15;
            sQr[kk][m] = Qr[(size_t)(row0 + m) * K + k0 + kk];
            sQi[kk][m] = Qi[(size_t)(row0 + m) * K + k0 + kk];
            sKr[kk][m] = Kr[(size_t)(col0 + m) * K + k0 + kk];
            sKi[kk][m] = Ki[(size_t)(col0 + m) * K + k0 + kk];
        }
        __syncthreads();
#pragma unroll
        for (int kk = 0; kk < BK; ++kk) {
            float q_r[4], q_i[4], k_r[4], k_i[4];
#pragma unroll
            for (int i = 0; i < 4; i++) { q_r[i] = sQr[kk][ty * 4 + i]; q_i[i] = sQi[kk][ty * 4 + i]; }
#pragma unroll
            for (int j = 0; j < 4; j++) { k_r[j] = sKr[kk][tx * 4 + j]; k_i[j] = sKi[kk][tx * 4 + j]; }
#pragma unroll
            for (int i = 0; i < 4; i++) {
#pragma unroll
                for (int j = 0; j < 4; j++) {
                    acc[i][j] += q_r[i] * k_r[j] + q_i[i] * k_i[j];
                }
            }
        }
        __syncthreads();
    }
#pragma unroll
    for (int i = 0; i < 4; i++) {
#pragma unroll
        for (int j = 0; j < 4; j++) {
            S[(size_t)(row0 + ty * 4 + i) * N + (col0 + tx * 4 + j)] = acc[i][j] * scale;
        }
    }
}

// ---------------------------------------------------------------------------
// Row softmax over N=2048, in place
// ---------------------------------------------------------------------------
__global__ __launch_bounds__(256) void k_softmax(float* __restrict__ S)
{
    const int row = blockIdx.x;
    float* p = S + (size_t)row * NTOK;
    __shared__ float red[256];
    float mx = -3.4e38f;
    for (int j = threadIdx.x; j < NTOK; j += 256) mx = fmaxf(mx, p[j]);
    red[threadIdx.x] = mx;
    __syncthreads();
    for (int st = 128; st > 0; st >>= 1) {
        if (threadIdx.x < st) red[threadIdx.x] = fmaxf(red[threadIdx.x], red[threadIdx.x + st]);
        __syncthreads();
    }
    mx = red[0];
    __syncthreads();
    float sum = 0.f;
    for (int j = threadIdx.x; j < NTOK; j += 256) {
        float e = expf(p[j] - mx);
        p[j] = e;
        sum += e;
    }
    red[threadIdx.x] = sum;
    __syncthreads();
    for (int st = 128; st > 0; st >>= 1) {
        if (threadIdx.x < st) red[threadIdx.x] += red[threadIdx.x + st];
        __syncthreads();
    }
    float inv = 1.0f / red[0];
    __syncthreads();
    for (int j = threadIdx.x; j < NTOK; j += 256) p[j] *= inv;
}

// ---------------------------------------------------------------------------
// A·V: Or = W*Vr, Oi = W*Vi  (W: M x K row-major, V: K x Ncol row-major)
// ---------------------------------------------------------------------------
__global__ __launch_bounds__(256) void k_av_gemm(
    const float* __restrict__ W, const float* __restrict__ Vr, const float* __restrict__ Vi,
    float* __restrict__ Or, float* __restrict__ Oi, int M, int Ncol, int K)
{
    __shared__ float sW[BK][BM + PAD];
    __shared__ float sVr[BK][BN + PAD], sVi[BK][BN + PAD];
    const int tid = threadIdx.x;
    const int tx = tid & 15, ty = tid >> 4;
    const int row0 = blockIdx.y * BM, col0 = blockIdx.x * BN;
    float cr[4][4] = {{0.f}}, ci[4][4] = {{0.f}};
    for (int k0 = 0; k0 < K; k0 += BK) {
        for (int l = tid; l < BM * BK; l += 256) {
            int m = l >> 4, kk = l & 15;
            sW[kk][m] = W[(size_t)(row0 + m) * K + k0 + kk];
        }
        for (int l = tid; l < BK * BN; l += 256) {
            int n = l & 63, kk = l >> 6;
            sVr[kk][n] = Vr[(size_t)(k0 + kk) * Ncol + col0 + n];
            sVi[kk][n] = Vi[(size_t)(k0 + kk) * Ncol + col0 + n];
        }
        __syncthreads();
#pragma unroll
        for (int kk = 0; kk < BK; ++kk) {
            float w[4], v_r[4], v_i[4];
#pragma unroll
            for (int i = 0; i < 4; i++) w[i] = sW[kk][ty * 4 + i];
#pragma unroll
            for (int j = 0; j < 4; j++) { v_r[j] = sVr[kk][tx * 4 + j]; v_i[j] = sVi[kk][tx * 4 + j]; }
#pragma unroll
            for (int i = 0; i < 4; i++) {
#pragma unroll
                for (int j = 0; j < 4; j++) {
                    cr[i][j] += w[i] * v_r[j];
                    ci[i][j] += w[i] * v_i[j];
                }
            }
        }
        __syncthreads();
    }
#pragma unroll
    for (int i = 0; i < 4; i++) {
#pragma unroll
        for (int j = 0; j < 4; j++) {
            size_t idx = (size_t)(row0 + ty * 4 + i) * Ncol + (col0 + tx * 4 + j);
            Or[idx] = cr[i][j];
            Oi[idx] = ci[i][j];
        }
    }
}

// ---------------------------------------------------------------------------
// Magnitude layernorm + focus + modReLU (in place on lr/li)
// ---------------------------------------------------------------------------
__global__ __launch_bounds__(256) void k_norm(
    float* __restrict__ lr, float* __restrict__ li,
    const float* __restrict__ scale, const float* __restrict__ shift,
    const float* __restrict__ focus, const float* __restrict__ modb)
{
    const int i = blockIdx.x;
    __shared__ float r1[256], r2[256];
    float s = 0.f, s2 = 0.f;
    for (int d = threadIdx.x; d < DIMD; d += 256) {
        float a = lr[(size_t)i * DIMD + d], b = li[(size_t)i * DIMD + d];
        float mag = sqrtf(a * a + b * b) + FEPS;
        s += mag;
        s2 += mag * mag;
    }
    r1[threadIdx.x] = s;
    r2[threadIdx.x] = s2;
    __syncthreads();
    for (int st = 128; st > 0; st >>= 1) {
        if (threadIdx.x < st) {
            r1[threadIdx.x] += r1[threadIdx.x + st];
            r2[threadIdx.x] += r2[threadIdx.x + st];
        }
        __syncthreads();
    }
    float mean = r1[0] / (float)DIMD;
    float var = (r2[0] - (float)DIMD * mean * mean) / (float)(DIMD - 1);
    float istd = 1.0f / sqrtf(var + FEPS);
    for (int d = threadIdx.x; d < DIMD; d += 256) {
        size_t idx = (size_t)i * DIMD + d;
        float a = lr[idx], b = li[idx];
        float mag = sqrtf(a * a + b * b) + FEPS;
        float nm = (mag - mean) * istd * scale[d] + shift[d];
        float x = nm * (a / mag), y = nm * (b / mag);
        float f = sigmoidf_(focus[d]);
        x *= f; y *= f;
        float nrm = sqrtf(x * x + y * y) + FEPS;
        float sc = fmaxf(nrm + modb[d], 0.0f) / nrm;
        lr[idx] = x * sc;
        li[idx] = y * sc;
    }
}

// ---------------------------------------------------------------------------
// halt = sigmoid(flat@halt_W^T + b); ctrl = softmax(flat@stack_W^T + b)
// ---------------------------------------------------------------------------
__global__ __launch_bounds__(256) void k_halt_ctrl(
    const float* __restrict__ ar, const float* __restrict__ ai,
    const float* __restrict__ hW, const float* __restrict__ hb,
    const float* __restrict__ stW, const float* __restrict__ stb,
    float* __restrict__ halt, float* __restrict__ ctrl)
{
    const int i = blockIdx.x;
    __shared__ float rh[256], r0[256], r1c[256], r2c[256];
    float sh = 0.f, s0 = 0.f, s1 = 0.f, s2 = 0.f;
    for (int d = threadIdx.x; d < DIMD; d += 256) {
        float a = ar[(size_t)i * DIMD + d], b = ai[(size_t)i * DIMD + d];
        sh += a * hW[d] + b * hW[DIMD + d];
        s0 += a * stW[d] + b * stW[DIMD + d];
        s1 += a * stW[2 * DIMD + d] + b * stW[3 * DIMD + d];
        s2 += a * stW[4 * DIMD + d] + b * stW[5 * DIMD + d];
    }
    rh[threadIdx.x] = sh; r0[threadIdx.x] = s0; r1c[threadIdx.x] = s1; r2c[threadIdx.x] = s2;
    __syncthreads();
    for (int st = 128; st > 0; st >>= 1) {
        if (threadIdx.x < st) {
            rh[threadIdx.x] += rh[threadIdx.x + st];
            r0[threadIdx.x] += r0[threadIdx.x + st];
            r1c[threadIdx.x] += r1c[threadIdx.x + st];
            r2c[threadIdx.x] += r2c[threadIdx.x + st];
        }
        __syncthreads();
    }
    if (threadIdx.x == 0) {
        float h = sigmoidf_(rh[0] + hb[0]);
        float a0 = r0[0] + stb[0], a1 = r1c[0] + stb[1], a2 = r2c[0] + stb[2];
        float m = fmaxf(a0, fmaxf(a1, a2));
        float e0 = expf(a0 - m), e1 = expf(a1 - m), e2 = expf(a2 - m);
        float is = 1.0f / (e0 + e1 + e2);
        halt[i] = h;
        ctrl[i * 3 + 0] = e0 * is;
        ctrl[i * 3 + 1] = e1 * is;
        ctrl[i * 3 + 2] = e2 * is;
    }
}

// ---------------------------------------------------------------------------
// Stack step via linearized memory coefficients.
// mem_t = sum_s alpha[s]*z_s ; read = sum_s (sum_j ptr[j]*alpha[s][j]) * z_s
// ---------------------------------------------------------------------------
__global__ __launch_bounds__(128) void k_stack(
    const float* __restrict__ ctrl, float* __restrict__ ptr,
    float* __restrict__ alpha, const float* __restrict__ zhist,
    float* __restrict__ rr, float* __restrict__ ri, int step)
{
    const int i = blockIdx.x;
    const int t = threadIdx.x;
    __shared__ float sp[SSTK], snew[SSTK], swm[SSTK];
    __shared__ float sal[NDEP][SSTK];
    __shared__ float c[NDEP];
    __shared__ float ssum;
    const float push = ctrl[i * 3 + 0], pop = ctrl[i * 3 + 1], noop = ctrl[i * 3 + 2];
    if (t < SSTK) {
        sp[t] = (step == 0) ? (t == 0 ? 1.0f : 0.0f) : ptr[(size_t)i * SSTK + t];
        for (int s = 0; s < step; s++)
            sal[s][t] = alpha[((size_t)i * NDEP + s) * SSTK + t];
    }
    __syncthreads();
    if (t < SSTK) {
        float up = sp[(t + SSTK - 1) & (SSTK - 1)];
        float dn = sp[(t + 1) & (SSTK - 1)];
        snew[t] = push * up + pop * dn + noop * sp[t];
        swm[t] = push * up;
    }
    __syncthreads();
    if (t == 0) {
        float s = 0.f;
        for (int j = 0; j < SSTK; j++) s += snew[j];
        ssum = s + FEPS;
    }
    __syncthreads();
    if (t < SSTK) {
        float np = snew[t] / ssum;
        snew[t] = np;
        ptr[(size_t)i * SSTK + t] = np;
        float w = swm[t];
        for (int s = 0; s < step; s++) {
            float v = sal[s][t] * (1.0f - w);
            sal[s][t] = v;
            alpha[((size_t)i * NDEP + s) * SSTK + t] = v;
        }
        sal[step][t] = w;
        alpha[((size_t)i * NDEP + step) * SSTK + t] = w;
    }
    __syncthreads();
    if (t <= step) {
        float cs = 0.f;
        for (int j = 0; j < SSTK; j++) cs += snew[j] * sal[t][j];
        c[t] = cs;
    }
    __syncthreads();
    for (int e = t; e < 2 * DIMD; e += 128) {
        float acc = 0.f;
        for (int s = 0; s <= step; s++) {
            const float* zf = zhist + (size_t)s * (2ull * NTOK * DIMD);
            float v = (e < DIMD) ? zf[(size_t)i * DIMD + e]
                                 : zf[(size_t)NTOK * DIMD + (size_t)i * DIMD + (e - DIMD)];
            acc += c[s] * v;
        }
        if (e < DIMD) rr[(size_t)i * DIMD + e] = acc;
        else          ri[(size_t)i * DIMD + (e - DIMD)] = acc;
    }
}

// ---------------------------------------------------------------------------
// Combine: nz = a + read ; halting pstep ; accumulate out ; z <- nz
// ---------------------------------------------------------------------------
__global__ __launch_bounds__(256) void k_combine(
    const float* __restrict__ ar, const float* __restrict__ ai,
    const float* __restrict__ rr, const float* __restrict__ ri,
    const float* __restrict__ halt, float* __restrict__ cum,
    float* __restrict__ zr, float* __restrict__ zi,
    float* __restrict__ outr, float* __restrict__ outi, int step)
{
    const int i = blockIdx.x;
    __shared__ float ps;
    if (threadIdx.x == 0) {
        float cm = cum[i];
        float h = halt[i];
        float still = (cm < FTHR) ? 1.0f : 0.0f;
        float p;
        if (step == NDEP - 1) p = (1.0f - cm) * still;
        else p = ((cm + h > FTHR) ? (1.0f - cm) : h) * still;
        cum[i] = cm + p;
        ps = p;
    }
    __syncthreads();
    float p = ps;
    for (int d = threadIdx.x; d < DIMD; d += 256) {
        size_t idx = (size_t)i * DIMD + d;
        float nzr = ar[idx] + rr[idx];
        float nzi = ai[idx] + ri[idx];
        outr[idx] += p * nzr;
        outi[idx] += p * nzi;
        zr[idx] = nzr;
        zi[idx] = nzi;
    }
}

// ---------------------------------------------------------------------------
// Final: logits = [outr|outi] @ out_W^T + out_b   (M x V, K=1024)
// ---------------------------------------------------------------------------
__global__ __launch_bounds__(256) void k_out_gemm(
    const float* __restrict__ Aor, const float* __restrict__ Aoi,
    const float* __restrict__ W, const float* __restrict__ bias,
    float* __restrict__ C, int M, int V)
{
    const int K = 2 * DIMD;
    __shared__ float sA[BK][BM + PAD], sB[BK][BN + PAD];
    const int tid = threadIdx.x;
    const int tx = tid & 15, ty = tid >> 4;
    const int row0 = blockIdx.y * BM, col0 = blockIdx.x * BN;
    float acc[4][4] = {{0.f}};
    for (int k0 = 0; k0 < K; k0 += BK) {
        for (int l = tid; l < BM * BK; l += 256) {
            int m = l >> 4, kk = l & 15;
            int k = k0 + kk;
            sA[kk][m] = (k < DIMD) ? Aor[(size_t)(row0 + m) * DIMD + k]
                                   : Aoi[(size_t)(row0 + m) * DIMD + (k - DIMD)];
            sB[kk][m] = W[(size_t)(col0 + m) * K + k];
        }
        __syncthreads();
#pragma unroll
        for (int kk = 0; kk < BK; ++kk) {
            float a[4], b[4];
#pragma unroll
            for (int i = 0; i < 4; i++) a[i] = sA[kk][ty * 4 + i];
#pragma unroll
            for (int j = 0; j < 4; j++) b[j] = sB[kk][tx * 4 + j];
#pragma unroll
            for (int i = 0; i < 4; i++) {
#pragma unroll
                for (int j = 0; j < 4; j++) acc[i][j] += a[i] * b[j];
            }
        }
        __syncthreads();
    }
#pragma unroll
    for (int i = 0; i < 4; i++) {
#pragma unroll
        for (int j = 0; j < 4; j++) {
            int cc = col0 + tx * 4 + j;
            C[(size_t)(row0 + ty * 4 + i) * V + cc] = acc[i][j] + bias[cc];
        }
    }
}

// ---------------------------------------------------------------------------
extern "C" void kernel_launch(void* const* d_in, const int* in_sizes, int n_in,
                              void* d_out, int out_size, void* d_ws, size_t ws_size,
                              hipStream_t stream)
{
    const int*   tokens  = (const int*)d_in[0];
    const float* emb_r   = (const float*)d_in[1];
    const float* emb_i   = (const float*)d_in[2];
    const float* lin_Wr  = (const float*)d_in[3];
    const float* lin_Wi  = (const float*)d_in[4];
    const float* ln_s    = (const float*)d_in[5];
    const float* ln_sh   = (const float*)d_in[6];
    const float* focus   = (const float*)d_in[7];
    const float* modb    = (const float*)d_in[8];
    const float* q_Wr    = (const float*)d_in[9];
    const float* q_Wi    = (const float*)d_in[10];
    const float* k_Wr    = (const float*)d_in[11];
    const float* k_Wi    = (const float*)d_in[12];
    const float* v_Wr    = (const float*)d_in[13];
    const float* v_Wi    = (const float*)d_in[14];
    const float* halt_W  = (const float*)d_in[15];
    const float* halt_b  = (const float*)d_in[16];
    const float* stack_W = (const float*)d_in[17];
    const float* stack_b = (const float*)d_in[18];
    const float* out_W   = (const float*)d_in[19];
    const float* out_b   = (const float*)d_in[20];
    float* logits = (float*)d_out;
    float* ws = (float*)d_ws;

    const size_t ND = (size_t)NTOK * DIMD;
    float* zr    = ws + 0 * ND;
    float* zi    = ws + 1 * ND;
    float* l_r   = ws + 2 * ND;   // lin out -> zr1 (in place after norm)
    float* l_i   = ws + 3 * ND;
    float* qr    = ws + 4 * ND;
    float* qi    = ws + 5 * ND;
    float* kr    = ws + 6 * ND;
    float* ki    = ws + 7 * ND;
    float* vr    = ws + 8 * ND;
    float* vi    = ws + 9 * ND;
    float* rr    = ws + 10 * ND;
    float* ri    = ws + 11 * ND;
    float* outr  = ws + 12 * ND;
    float* outi  = ws + 13 * ND;
    float* sc    = ws + 14 * ND;            // NTOK*NTOK = 4*ND floats
    float* zhist = ws + 18 * ND;            // NDEP * 2 * ND floats
    float* ptr   = ws + 34 * ND;
    float* alpha = ptr + (size_t)NTOK * SSTK;
    float* cum   = alpha + (size_t)NTOK * NDEP * SSTK;
    float* halt  = cum + NTOK;
    float* ctrl  = halt + NTOK;

    const float scale = 0.044194173824159216f; // 512^-0.5

    k_embed<<<NTOK, 256, 0, stream>>>(tokens, emb_r, emb_i, zr, zi, outr, outi, cum);

    dim3 gD(DIMD / BN, NTOK / BM);   // 8 x 32
    dim3 gS(NTOK / BN, NTOK / BM);   // 32 x 32

    for (int step = 0; step < NDEP; ++step) {
        float* ar = zhist + (size_t)step * 2 * ND;
        float* ai = ar + ND;

        k_cgemm_nt<<<gD, 256, 0, stream>>>(zr, zi, lin_Wr, lin_Wi, l_r, l_i, NTOK, DIMD, DIMD);
        k_norm<<<NTOK, 256, 0, stream>>>(l_r, l_i, ln_s, ln_sh, focus, modb);
        k_cgemm_nt<<<gD, 256, 0, stream>>>(l_r, l_i, q_Wr, q_Wi, qr, qi, NTOK, DIMD, DIMD);
        k_cgemm_nt<<<gD, 256, 0, stream>>>(l_r, l_i, k_Wr, k_Wi, kr, ki, NTOK, DIMD, DIMD);
        k_cgemm_nt<<<gD, 256, 0, stream>>>(l_r, l_i, v_Wr, v_Wi, vr, vi, NTOK, DIMD, DIMD);
        k_score_gemm<<<gS, 256, 0, stream>>>(qr, qi, kr, ki, sc, NTOK, DIMD, scale);
        k_softmax<<<NTOK, 256, 0, stream>>>(sc);
        k_av_gemm<<<gD, 256, 0, stream>>>(sc, vr, vi, ar, ai, NTOK, DIMD, NTOK);
        k_halt_ctrl<<<NTOK, 256, 0, stream>>>(ar, ai, halt_W, halt_b, stack_W, stack_b, halt, ctrl);
        k_stack<<<NTOK, 128, 0, stream>>>(ctrl, ptr, alpha, zhist, rr, ri, step);
        k_combine<<<NTOK, 256, 0, stream>>>(ar, ai, rr, ri, halt, cum, zr, zi, outr, outi, step);
    }

    dim3 gO(VOC / BN, NTOK / BM);    // 500 x 32
    k_out_gemm<<<gO, 256, 0, stream>>>(outr, outi, out_W, out_b, logits, NTOK, VOC);
}